// Round 2
// baseline (249.827 us; speedup 1.0000x reference)
//
#include <hip/hip_runtime.h>

// ---------------------------------------------------------------------------
// CrossRNN: embed-gather -> 2-layer Elman RNN (relu) -> row/col cross -> dot
// B=4 R=64 C=64 S=32 V=30000 E=H=128 L=2   N = B*R*C = 16384 sequences
//
//  k_t1   : T1[v,h] = embed[v,:]·W_ih[0][h,:] + b_ih[0][h]   (30000x128 f32)
//  k_rnn  : fused 2-layer RNN, layer-skewed, 1 raw s_barrier per step,
//           distance-2 T1-gather prefetch kept in flight across barriers,
//           conflict-free (row<<4) XOR-swizzled LDS h-buffers.
//  k_final: out = s1 + rowsum(s2) + colsum(s2) - 2*s2 + pred_b
// ---------------------------------------------------------------------------

typedef __attribute__((ext_vector_type(8))) short short8;
typedef __attribute__((ext_vector_type(4))) float f32x4;

#define Hd 128
#define Sd 32
#define NSEQ 16
#define VROWS 30000
#define NTILES 1875  // 30000/16 exact

__device__ __forceinline__ unsigned short f2b(float f) {
  unsigned int u = __float_as_uint(f);
  u += 0x7FFFu + ((u >> 16) & 1u);  // RNE
  return (unsigned short)(u >> 16);
}

__device__ __forceinline__ f32x4 mfma16(short8 a, short8 b, f32x4 c) {
  return __builtin_amdgcn_mfma_f32_16x16x32_bf16(a, b, c, 0, 0, 0);
}

// load 8 consecutive f32 (32B aligned) -> bf16 fragment
__device__ __forceinline__ short8 load_row8_bf16(const float* __restrict__ p) {
  const float4* q = reinterpret_cast<const float4*>(p);
  float4 a = q[0], b = q[1];
  short8 s;
  s[0] = (short)f2b(a.x); s[1] = (short)f2b(a.y);
  s[2] = (short)f2b(a.z); s[3] = (short)f2b(a.w);
  s[4] = (short)f2b(b.x); s[5] = (short)f2b(b.y);
  s[6] = (short)f2b(b.z); s[7] = (short)f2b(b.w);
  return s;
}

// ---------------------------------------------------------------------------
// K1: T1 = embed @ W_ih[0]^T + b_ih[0].  235 blocks x 256 thr; each wave
// holds B-fragments of the whole W (128 VGPR) and loops over 2 M-tiles.
// ---------------------------------------------------------------------------
__global__ __launch_bounds__(256, 2) void k_t1(const float* __restrict__ embed,
                                               const float* __restrict__ W_ih,
                                               const float* __restrict__ b_ih,
                                               float* __restrict__ T1) {
  const int tid = threadIdx.x, lane = tid & 63, wid = tid >> 6;
  const int l15 = lane & 15, lg = lane >> 4;
  const int gw = blockIdx.x * 4 + wid;  // 0..939

  short8 Bf[8][4];
  float bi[8];
#pragma unroll
  for (int nt = 0; nt < 8; ++nt) {
    int h = nt * 16 + l15;
#pragma unroll
    for (int kt = 0; kt < 4; ++kt)
      Bf[nt][kt] = load_row8_bf16(W_ih + h * Hd + kt * 32 + lg * 8);
    bi[nt] = b_ih[h];
  }

  for (int tt = gw; tt < NTILES; tt += 940) {
    const int v = tt * 16 + l15;
    short8 Af[4];
#pragma unroll
    for (int kt = 0; kt < 4; ++kt)
      Af[kt] = load_row8_bf16(embed + v * Hd + kt * 32 + lg * 8);
    f32x4 C[8];
#pragma unroll
    for (int nt = 0; nt < 8; ++nt) C[nt] = (f32x4){bi[nt], bi[nt], bi[nt], bi[nt]};
#pragma unroll
    for (int kt = 0; kt < 4; ++kt) {
#pragma unroll
      for (int nt = 0; nt < 8; ++nt) C[nt] = mfma16(Af[kt], Bf[nt][kt], C[nt]);
    }
    const int vout = tt * 16 + lg * 4;
#pragma unroll
    for (int nt = 0; nt < 8; ++nt) {
      int colh = nt * 16 + l15;
#pragma unroll
      for (int r = 0; r < 4; ++r) T1[(vout + r) * Hd + colh] = C[nt][r];
    }
  }
}

// ---------------------------------------------------------------------------
// K2: fused RNN. 1024 blocks x 512 thr (8 waves); wave owns 16 output cols.
// ---------------------------------------------------------------------------
#define LDR(BUF, kt)                                                       \
  (*reinterpret_cast<const short8*>(reinterpret_cast<const char*>(BUF) +   \
                                    rbase + ((kt * 64) ^ rxor)))
#define HW16(BUF, OFF, F)                                                  \
  (*reinterpret_cast<unsigned short*>(reinterpret_cast<char*>(BUF) +       \
                                      (OFF)) = f2b(F))

#define STEP(T, T1V, H1B, H2B)                                             \
  {                                                                        \
    float m0 = T1V[0], m1 = T1V[1], m2 = T1V[2], m3 = T1V[3];              \
    {                                                                      \
      const int tp = (T) + 2;                                              \
      T1V[0] = T1[(size_t)xs[xrow0 + tp] * Hd + c];                        \
      T1V[1] = T1[(size_t)xs[xrow1 + tp] * Hd + c];                        \
      T1V[2] = T1[(size_t)xs[xrow2 + tp] * Hd + c];                        \
      T1V[3] = T1[(size_t)xs[xrow3 + tp] * Hd + c];                        \
    }                                                                      \
    f32x4 C1 = (f32x4){bh0, bh0, bh0, bh0};                                \
    _Pragma("unroll") for (int kt = 0; kt < 4; ++kt)                       \
        C1 = mfma16(h1f[kt], Wh0f[kt], C1);                                \
    C1[0] = fmaxf(C1[0] + m0, 0.f); C1[1] = fmaxf(C1[1] + m1, 0.f);        \
    C1[2] = fmaxf(C1[2] + m2, 0.f); C1[3] = fmaxf(C1[3] + m3, 0.f);        \
    HW16(H1B, woff0, C1[0]); HW16(H1B, woff1, C1[1]);                      \
    HW16(H1B, woff2, C1[2]); HW16(H1B, woff3, C1[3]);                      \
    f32x4 Ca = (f32x4){bsum, bsum, bsum, bsum};                            \
    f32x4 Cb = (f32x4){0.f, 0.f, 0.f, 0.f};                                \
    _Pragma("unroll") for (int kt = 0; kt < 4; ++kt) {                     \
      Ca = mfma16(h1f[kt], Wi1f[kt], Ca);                                  \
      Cb = mfma16(h2f[kt], Wh1f[kt], Cb);                                  \
    }                                                                      \
    Ca[0] = fmaxf(Ca[0] + Cb[0], 0.f); Ca[1] = fmaxf(Ca[1] + Cb[1], 0.f);  \
    Ca[2] = fmaxf(Ca[2] + Cb[2], 0.f); Ca[3] = fmaxf(Ca[3] + Cb[3], 0.f);  \
    HW16(H2B, woff0, Ca[0]); HW16(H2B, woff1, Ca[1]);                      \
    HW16(H2B, woff2, Ca[2]); HW16(H2B, woff3, Ca[3]);                      \
    asm volatile("s_waitcnt lgkmcnt(0)" ::: "memory");                     \
    __builtin_amdgcn_s_barrier();                                          \
    _Pragma("unroll") for (int kt = 0; kt < 4; ++kt) {                     \
      h1f[kt] = LDR(H1B, kt);                                              \
      h2f[kt] = LDR(H2B, kt);                                              \
    }                                                                      \
  }

__global__ __launch_bounds__(512, 4) void k_rnn(
    const int* __restrict__ x, const float* __restrict__ T1,
    const float* __restrict__ W_ih, const float* __restrict__ W_hh,
    const float* __restrict__ b_ih, const float* __restrict__ b_hh,
    const float* __restrict__ pred_W, float* __restrict__ sbuf) {
  __shared__ alignas(16) unsigned short h1b0[NSEQ * Hd];  // 4KB each
  __shared__ alignas(16) unsigned short h1b1[NSEQ * Hd];
  __shared__ alignas(16) unsigned short h2b0[NSEQ * Hd];
  __shared__ alignas(16) unsigned short h2b1[NSEQ * Hd];
  __shared__ int xs[NSEQ * Sd + 64];
  __shared__ float sred[8][16][2];

  const int tid = threadIdx.x, lane = tid & 63, ns = tid >> 6;  // ns: 0..7
  const int l15 = lane & 15, lg = lane >> 4;
  const int seq0 = blockIdx.x * NSEQ;
  const int c = ns * 16 + l15;  // this wave's output column

  // LDS addressing (conflict-free XOR swizzle, (row)<<4)
  const int rbase = l15 * 256;
  const int rxor = (lg * 16) ^ (l15 << 4);
  const int row0 = lg * 4;
  const int woff0 = (row0 + 0) * 256 + ((c * 2) ^ ((row0 + 0) << 4));
  const int woff1 = (row0 + 1) * 256 + ((c * 2) ^ ((row0 + 1) << 4));
  const int woff2 = (row0 + 2) * 256 + ((c * 2) ^ ((row0 + 2) << 4));
  const int woff3 = (row0 + 3) * 256 + ((c * 2) ^ ((row0 + 3) << 4));
  const int xrow0 = (lg * 4 + 0) * Sd, xrow1 = (lg * 4 + 1) * Sd;
  const int xrow2 = (lg * 4 + 2) * Sd, xrow3 = (lg * 4 + 3) * Sd;

  // stage x indices (+ zero pad so prefetch of t=32,33 stays in-bounds)
  xs[tid] = x[seq0 * Sd + tid];
  if (tid < 64) xs[NSEQ * Sd + tid] = 0;

  // per-wave weight fragments (16 cols each)
  short8 Wh0f[4], Wi1f[4], Wh1f[4];
#pragma unroll
  for (int kt = 0; kt < 4; ++kt) {
    Wh0f[kt] = load_row8_bf16(W_hh + c * Hd + kt * 32 + lg * 8);
    Wi1f[kt] = load_row8_bf16(W_ih + Hd * Hd + c * Hd + kt * 32 + lg * 8);
    Wh1f[kt] = load_row8_bf16(W_hh + Hd * Hd + c * Hd + kt * 32 + lg * 8);
  }
  const float bh0 = b_hh[c];
  const float bsum = b_ih[Hd + c] + b_hh[Hd + c];
  const float pw1 = pred_W[c];
  const float pw2 = pred_W[Hd + c];
  __syncthreads();  // xs visible

  float t1A[4], t1B[4];
#pragma unroll
  for (int r = 0; r < 4; ++r) {
    t1A[r] = T1[(size_t)xs[(lg * 4 + r) * Sd + 0] * Hd + c];
    t1B[r] = T1[(size_t)xs[(lg * 4 + r) * Sd + 1] * Hd + c];
  }

  short8 h1f[4], h2f[4];
  // h1_0 = relu(T1x0 + bh0)
  {
    f32x4 C0;
#pragma unroll
    for (int r = 0; r < 4; ++r) C0[r] = fmaxf(t1A[r] + bh0, 0.f);
    HW16(h1b0, woff0, C0[0]); HW16(h1b0, woff1, C0[1]);
    HW16(h1b0, woff2, C0[2]); HW16(h1b0, woff3, C0[3]);
  }
  // prefetch t=2
#pragma unroll
  for (int r = 0; r < 4; ++r)
    t1A[r] = T1[(size_t)xs[(lg * 4 + r) * Sd + 2] * Hd + c];
  asm volatile("s_waitcnt lgkmcnt(0)" ::: "memory");
  __builtin_amdgcn_s_barrier();
#pragma unroll
  for (int kt = 0; kt < 4; ++kt) {
    h1f[kt] = LDR(h1b0, kt);
    h2f[kt] = (short8){0, 0, 0, 0, 0, 0, 0, 0};
  }

  STEP(1, t1B, h1b1, h2b1)
  for (int k = 1; k <= 15; ++k) {
    STEP(2 * k, t1A, h1b0, h2b0)
    STEP(2 * k + 1, t1B, h1b1, h2b1)
  }
  // after loop: h1f = h1_31, h2f = h2_30 -> final h2_31 (stays in registers)
  float p1[4], p2[4];
  {
    f32x4 Ca = (f32x4){bsum, bsum, bsum, bsum};
    f32x4 Cb = (f32x4){0.f, 0.f, 0.f, 0.f};
#pragma unroll
    for (int kt = 0; kt < 4; ++kt) {
      Ca = mfma16(h1f[kt], Wi1f[kt], Ca);
      Cb = mfma16(h2f[kt], Wh1f[kt], Cb);
    }
#pragma unroll
    for (int r = 0; r < 4; ++r) {
      float v = fmaxf(Ca[r] + Cb[r], 0.f);
      p1[r] = v * pw1;
      p2[r] = v * pw2;
    }
  }
#pragma unroll
  for (int m = 1; m < 16; m <<= 1) {
#pragma unroll
    for (int r = 0; r < 4; ++r) {
      p1[r] += __shfl_xor(p1[r], m);
      p2[r] += __shfl_xor(p2[r], m);
    }
  }
  if (l15 == 0) {
#pragma unroll
    for (int r = 0; r < 4; ++r) {
      sred[ns][lg * 4 + r][0] = p1[r];
      sred[ns][lg * 4 + r][1] = p2[r];
    }
  }
  __syncthreads();
  if (tid < 32) {
    int nl = tid >> 1, st = tid & 1;
    float v = 0.f;
#pragma unroll
    for (int w = 0; w < 8; ++w) v += sred[w][nl][st];
    sbuf[st * 16384 + seq0 + nl] = v;
  }
}

// ---------------------------------------------------------------------------
// K3: out[b,r,c] = s1 + rowsum_c(s2) + colsum_r(s2) - 2*s2 + pred_b
// ---------------------------------------------------------------------------
__global__ __launch_bounds__(1024) void k_final(const float* __restrict__ sbuf,
                                                const float* __restrict__ pred_b,
                                                float* __restrict__ out) {
  __shared__ float s2s[64][65];
  __shared__ float rowS[64], colS[64];
  const int b = blockIdx.x, tid = threadIdx.x;
  const float* s1g = sbuf + b * 4096;
  const float* s2g = sbuf + 16384 + b * 4096;
#pragma unroll
  for (int i = 0; i < 4; ++i) {
    int j = tid + i * 1024;
    s2s[j >> 6][j & 63] = s2g[j];
  }
  __syncthreads();
  if (tid < 64) {
    float s = 0.f;
    for (int cc = 0; cc < 64; ++cc) s += s2s[tid][cc];
    rowS[tid] = s;
  } else if (tid < 128) {
    int cc = tid - 64;
    float s = 0.f;
    for (int r = 0; r < 64; ++r) s += s2s[r][cc];
    colS[cc] = s;
  }
  __syncthreads();
  const float pb = pred_b[0];
#pragma unroll
  for (int i = 0; i < 4; ++i) {
    int j = tid + i * 1024;
    int r = j >> 6, cc = j & 63;
    out[b * 4096 + j] = s1g[j] + rowS[r] + colS[cc] - 2.f * s2s[r][cc] + pb;
  }
}

// ---------------------------------------------------------------------------
extern "C" void kernel_launch(void* const* d_in, const int* in_sizes, int n_in,
                              void* d_out, int out_size, void* d_ws,
                              size_t ws_size, hipStream_t stream) {
  const int* x = (const int*)d_in[0];
  const float* embed = (const float*)d_in[1];
  const float* W_ih = (const float*)d_in[2];
  const float* W_hh = (const float*)d_in[3];
  const float* b_ih = (const float*)d_in[4];
  const float* b_hh = (const float*)d_in[5];
  const float* pred_W = (const float*)d_in[6];
  const float* pred_b = (const float*)d_in[7];

  float* T1 = (float*)d_ws;       // 30000*128 f32 = 15.36 MB
  float* sbuf = T1 + VROWS * Hd;  // 2*16384 f32
  float* out = (float*)d_out;

  k_t1<<<235, 256, 0, stream>>>(embed, W_ih, b_ih, T1);
  k_rnn<<<16384 / NSEQ, 512, 0, stream>>>(x, T1, W_ih, W_hh, b_ih, b_hh,
                                          pred_W, sbuf);
  k_final<<<4, 1024, 0, stream>>>(sbuf, pred_b, out);
}

// Round 3
// 193.979 us; speedup vs baseline: 1.2879x; 1.2879x over previous
//
#include <hip/hip_runtime.h>
#include <hip/hip_bf16.h>

// ---------------------------------------------------------------------------
// CrossRNN: embed-gather -> 2-layer Elman RNN (relu) -> row/col cross -> dot
// B=4 R=64 C=64 S=32 V=30000 E=H=128 L=2   N = B*R*C = 16384 sequences
//
//  k_t1   : T1[v,h] = embed[v,:]·W_ih[0][h,:] + b_ih[0][h]   (30000x128 f32)
//  k_rnn  : fused 2-layer RNN, layer-skewed, 1 raw s_barrier per step,
//           distance-2 T1-gather prefetch kept in flight across barriers,
//           conflict-free (row<<4) XOR-swizzled LDS h-buffers.
//           8 waves x 16 cols/wave; ~120 VGPR -> launch_bounds(512,2)
//           (NOT (512,4): that caps VGPR at 64 and spills the weight regs —
//            measured round 2: WRITE_SIZE 125MB of scratch, 1.7x slower)
//  k_final: out = s1 + rowsum(s2) + colsum(s2) - 2*s2 + pred_b
// ---------------------------------------------------------------------------

typedef __attribute__((ext_vector_type(8))) short short8;
typedef __attribute__((ext_vector_type(4))) float f32x4;

#define Hd 128
#define Sd 32
#define NSEQ 16
#define VROWS 30000
#define NTILES 1875  // 30000/16 exact

// native RNE f32->bf16 (compiler emits v_cvt_pk_bf16_f32, schedulable)
__device__ __forceinline__ unsigned short f2b(float f) {
  __hip_bfloat16 h = __float2bfloat16(f);
  return reinterpret_cast<unsigned short&>(h);
}

__device__ __forceinline__ f32x4 mfma16(short8 a, short8 b, f32x4 c) {
  return __builtin_amdgcn_mfma_f32_16x16x32_bf16(a, b, c, 0, 0, 0);
}

// load 8 consecutive f32 (32B aligned) -> bf16 fragment
__device__ __forceinline__ short8 load_row8_bf16(const float* __restrict__ p) {
  const float4* q = reinterpret_cast<const float4*>(p);
  float4 a = q[0], b = q[1];
  short8 s;
  s[0] = (short)f2b(a.x); s[1] = (short)f2b(a.y);
  s[2] = (short)f2b(a.z); s[3] = (short)f2b(a.w);
  s[4] = (short)f2b(b.x); s[5] = (short)f2b(b.y);
  s[6] = (short)f2b(b.z); s[7] = (short)f2b(b.w);
  return s;
}

// ---------------------------------------------------------------------------
// K1: T1 = embed @ W_ih[0]^T + b_ih[0].  235 blocks x 256 thr; each wave
// holds B-fragments of the whole W (128 VGPR) and loops over 2 M-tiles.
// ---------------------------------------------------------------------------
__global__ __launch_bounds__(256, 2) void k_t1(const float* __restrict__ embed,
                                               const float* __restrict__ W_ih,
                                               const float* __restrict__ b_ih,
                                               float* __restrict__ T1) {
  const int tid = threadIdx.x, lane = tid & 63, wid = tid >> 6;
  const int l15 = lane & 15, lg = lane >> 4;
  const int gw = blockIdx.x * 4 + wid;  // 0..939

  short8 Bf[8][4];
  float bi[8];
#pragma unroll
  for (int nt = 0; nt < 8; ++nt) {
    int h = nt * 16 + l15;
#pragma unroll
    for (int kt = 0; kt < 4; ++kt)
      Bf[nt][kt] = load_row8_bf16(W_ih + h * Hd + kt * 32 + lg * 8);
    bi[nt] = b_ih[h];
  }

  for (int tt = gw; tt < NTILES; tt += 940) {
    const int v = tt * 16 + l15;
    short8 Af[4];
#pragma unroll
    for (int kt = 0; kt < 4; ++kt)
      Af[kt] = load_row8_bf16(embed + v * Hd + kt * 32 + lg * 8);
    f32x4 C[8];
#pragma unroll
    for (int nt = 0; nt < 8; ++nt) C[nt] = (f32x4){bi[nt], bi[nt], bi[nt], bi[nt]};
#pragma unroll
    for (int kt = 0; kt < 4; ++kt) {
#pragma unroll
      for (int nt = 0; nt < 8; ++nt) C[nt] = mfma16(Af[kt], Bf[nt][kt], C[nt]);
    }
    const int vout = tt * 16 + lg * 4;
#pragma unroll
    for (int nt = 0; nt < 8; ++nt) {
      int colh = nt * 16 + l15;
#pragma unroll
      for (int r = 0; r < 4; ++r) T1[(vout + r) * Hd + colh] = C[nt][r];
    }
  }
}

// ---------------------------------------------------------------------------
// K2: fused RNN. 1024 blocks x 512 thr (8 waves); wave owns 16 output cols.
// ---------------------------------------------------------------------------
#define LDR(BUF, kt)                                                       \
  (*reinterpret_cast<const short8*>(reinterpret_cast<const char*>(BUF) +   \
                                    rbase + ((kt * 64) ^ rxor)))
#define HW16(BUF, OFF, F)                                                  \
  (*reinterpret_cast<unsigned short*>(reinterpret_cast<char*>(BUF) +       \
                                      (OFF)) = f2b(F))

#define STEP(T, T1V, H1B, H2B)                                             \
  {                                                                        \
    float m0 = T1V[0], m1 = T1V[1], m2 = T1V[2], m3 = T1V[3];              \
    {                                                                      \
      const int tp = (T) + 2;                                              \
      T1V[0] = T1[(size_t)xs[xrow0 + tp] * Hd + c];                        \
      T1V[1] = T1[(size_t)xs[xrow1 + tp] * Hd + c];                        \
      T1V[2] = T1[(size_t)xs[xrow2 + tp] * Hd + c];                        \
      T1V[3] = T1[(size_t)xs[xrow3 + tp] * Hd + c];                        \
    }                                                                      \
    f32x4 C1 = (f32x4){bh0, bh0, bh0, bh0};                                \
    _Pragma("unroll") for (int kt = 0; kt < 4; ++kt)                       \
        C1 = mfma16(h1f[kt], Wh0f[kt], C1);                                \
    C1[0] = fmaxf(C1[0] + m0, 0.f); C1[1] = fmaxf(C1[1] + m1, 0.f);        \
    C1[2] = fmaxf(C1[2] + m2, 0.f); C1[3] = fmaxf(C1[3] + m3, 0.f);        \
    HW16(H1B, woff0, C1[0]); HW16(H1B, woff1, C1[1]);                      \
    HW16(H1B, woff2, C1[2]); HW16(H1B, woff3, C1[3]);                      \
    f32x4 Ca = (f32x4){bsum, bsum, bsum, bsum};                            \
    f32x4 Cb = (f32x4){0.f, 0.f, 0.f, 0.f};                                \
    _Pragma("unroll") for (int kt = 0; kt < 4; ++kt) {                     \
      Ca = mfma16(h1f[kt], Wi1f[kt], Ca);                                  \
      Cb = mfma16(h2f[kt], Wh1f[kt], Cb);                                  \
    }                                                                      \
    Ca[0] = fmaxf(Ca[0] + Cb[0], 0.f); Ca[1] = fmaxf(Ca[1] + Cb[1], 0.f);  \
    Ca[2] = fmaxf(Ca[2] + Cb[2], 0.f); Ca[3] = fmaxf(Ca[3] + Cb[3], 0.f);  \
    HW16(H2B, woff0, Ca[0]); HW16(H2B, woff1, Ca[1]);                      \
    HW16(H2B, woff2, Ca[2]); HW16(H2B, woff3, Ca[3]);                      \
    asm volatile("s_waitcnt lgkmcnt(0)" ::: "memory");                     \
    __builtin_amdgcn_s_barrier();                                          \
    _Pragma("unroll") for (int kt = 0; kt < 4; ++kt) {                     \
      h1f[kt] = LDR(H1B, kt);                                              \
      h2f[kt] = LDR(H2B, kt);                                              \
    }                                                                      \
  }

__global__ __launch_bounds__(512, 2) void k_rnn(
    const int* __restrict__ x, const float* __restrict__ T1,
    const float* __restrict__ W_ih, const float* __restrict__ W_hh,
    const float* __restrict__ b_ih, const float* __restrict__ b_hh,
    const float* __restrict__ pred_W, float* __restrict__ sbuf) {
  __shared__ alignas(16) unsigned short h1b0[NSEQ * Hd];  // 4KB each
  __shared__ alignas(16) unsigned short h1b1[NSEQ * Hd];
  __shared__ alignas(16) unsigned short h2b0[NSEQ * Hd];
  __shared__ alignas(16) unsigned short h2b1[NSEQ * Hd];
  __shared__ int xs[NSEQ * Sd + 64];
  __shared__ float sred[8][16][2];

  const int tid = threadIdx.x, lane = tid & 63, ns = tid >> 6;  // ns: 0..7
  const int l15 = lane & 15, lg = lane >> 4;
  const int seq0 = blockIdx.x * NSEQ;
  const int c = ns * 16 + l15;  // this wave's output column

  // LDS addressing (conflict-free XOR swizzle, (row)<<4)
  const int rbase = l15 * 256;
  const int rxor = (lg * 16) ^ (l15 << 4);
  const int row0 = lg * 4;
  const int woff0 = (row0 + 0) * 256 + ((c * 2) ^ ((row0 + 0) << 4));
  const int woff1 = (row0 + 1) * 256 + ((c * 2) ^ ((row0 + 1) << 4));
  const int woff2 = (row0 + 2) * 256 + ((c * 2) ^ ((row0 + 2) << 4));
  const int woff3 = (row0 + 3) * 256 + ((c * 2) ^ ((row0 + 3) << 4));
  const int xrow0 = (lg * 4 + 0) * Sd, xrow1 = (lg * 4 + 1) * Sd;
  const int xrow2 = (lg * 4 + 2) * Sd, xrow3 = (lg * 4 + 3) * Sd;

  // stage x indices (+ zero pad so prefetch of t=32,33 stays in-bounds)
  xs[tid] = x[seq0 * Sd + tid];
  if (tid < 64) xs[NSEQ * Sd + tid] = 0;

  // per-wave weight fragments (16 cols each)
  short8 Wh0f[4], Wi1f[4], Wh1f[4];
#pragma unroll
  for (int kt = 0; kt < 4; ++kt) {
    Wh0f[kt] = load_row8_bf16(W_hh + c * Hd + kt * 32 + lg * 8);
    Wi1f[kt] = load_row8_bf16(W_ih + Hd * Hd + c * Hd + kt * 32 + lg * 8);
    Wh1f[kt] = load_row8_bf16(W_hh + Hd * Hd + c * Hd + kt * 32 + lg * 8);
  }
  const float bh0 = b_hh[c];
  const float bsum = b_ih[Hd + c] + b_hh[Hd + c];
  const float pw1 = pred_W[c];
  const float pw2 = pred_W[Hd + c];
  __syncthreads();  // xs visible

  float t1A[4], t1B[4];
#pragma unroll
  for (int r = 0; r < 4; ++r) {
    t1A[r] = T1[(size_t)xs[(lg * 4 + r) * Sd + 0] * Hd + c];
    t1B[r] = T1[(size_t)xs[(lg * 4 + r) * Sd + 1] * Hd + c];
  }

  short8 h1f[4], h2f[4];
  // h1_0 = relu(T1x0 + bh0)
  {
    f32x4 C0;
#pragma unroll
    for (int r = 0; r < 4; ++r) C0[r] = fmaxf(t1A[r] + bh0, 0.f);
    HW16(h1b0, woff0, C0[0]); HW16(h1b0, woff1, C0[1]);
    HW16(h1b0, woff2, C0[2]); HW16(h1b0, woff3, C0[3]);
  }
  // prefetch t=2
#pragma unroll
  for (int r = 0; r < 4; ++r)
    t1A[r] = T1[(size_t)xs[(lg * 4 + r) * Sd + 2] * Hd + c];
  asm volatile("s_waitcnt lgkmcnt(0)" ::: "memory");
  __builtin_amdgcn_s_barrier();
#pragma unroll
  for (int kt = 0; kt < 4; ++kt) {
    h1f[kt] = LDR(h1b0, kt);
    h2f[kt] = (short8){0, 0, 0, 0, 0, 0, 0, 0};
  }

  STEP(1, t1B, h1b1, h2b1)
  for (int k = 1; k <= 15; ++k) {
    STEP(2 * k, t1A, h1b0, h2b0)
    STEP(2 * k + 1, t1B, h1b1, h2b1)
  }
  // after loop: h1f = h1_31, h2f = h2_30 -> final h2_31 (stays in registers)
  float p1[4], p2[4];
  {
    f32x4 Ca = (f32x4){bsum, bsum, bsum, bsum};
    f32x4 Cb = (f32x4){0.f, 0.f, 0.f, 0.f};
#pragma unroll
    for (int kt = 0; kt < 4; ++kt) {
      Ca = mfma16(h1f[kt], Wi1f[kt], Ca);
      Cb = mfma16(h2f[kt], Wh1f[kt], Cb);
    }
#pragma unroll
    for (int r = 0; r < 4; ++r) {
      float v = fmaxf(Ca[r] + Cb[r], 0.f);
      p1[r] = v * pw1;
      p2[r] = v * pw2;
    }
  }
#pragma unroll
  for (int m = 1; m < 16; m <<= 1) {
#pragma unroll
    for (int r = 0; r < 4; ++r) {
      p1[r] += __shfl_xor(p1[r], m);
      p2[r] += __shfl_xor(p2[r], m);
    }
  }
  if (l15 == 0) {
#pragma unroll
    for (int r = 0; r < 4; ++r) {
      sred[ns][lg * 4 + r][0] = p1[r];
      sred[ns][lg * 4 + r][1] = p2[r];
    }
  }
  __syncthreads();
  if (tid < 32) {
    int nl = tid >> 1, st = tid & 1;
    float v = 0.f;
#pragma unroll
    for (int w = 0; w < 8; ++w) v += sred[w][nl][st];
    sbuf[st * 16384 + seq0 + nl] = v;
  }
}

// ---------------------------------------------------------------------------
// K3: out[b,r,c] = s1 + rowsum_c(s2) + colsum_r(s2) - 2*s2 + pred_b
// ---------------------------------------------------------------------------
__global__ __launch_bounds__(1024) void k_final(const float* __restrict__ sbuf,
                                                const float* __restrict__ pred_b,
                                                float* __restrict__ out) {
  __shared__ float s2s[64][65];
  __shared__ float rowS[64], colS[64];
  const int b = blockIdx.x, tid = threadIdx.x;
  const float* s1g = sbuf + b * 4096;
  const float* s2g = sbuf + 16384 + b * 4096;
#pragma unroll
  for (int i = 0; i < 4; ++i) {
    int j = tid + i * 1024;
    s2s[j >> 6][j & 63] = s2g[j];
  }
  __syncthreads();
  if (tid < 64) {
    float s = 0.f;
    for (int cc = 0; cc < 64; ++cc) s += s2s[tid][cc];
    rowS[tid] = s;
  } else if (tid < 128) {
    int cc = tid - 64;
    float s = 0.f;
    for (int r = 0; r < 64; ++r) s += s2s[r][cc];
    colS[cc] = s;
  }
  __syncthreads();
  const float pb = pred_b[0];
#pragma unroll
  for (int i = 0; i < 4; ++i) {
    int j = tid + i * 1024;
    int r = j >> 6, cc = j & 63;
    out[b * 4096 + j] = s1g[j] + rowS[r] + colS[cc] - 2.f * s2s[r][cc] + pb;
  }
}

// ---------------------------------------------------------------------------
extern "C" void kernel_launch(void* const* d_in, const int* in_sizes, int n_in,
                              void* d_out, int out_size, void* d_ws,
                              size_t ws_size, hipStream_t stream) {
  const int* x = (const int*)d_in[0];
  const float* embed = (const float*)d_in[1];
  const float* W_ih = (const float*)d_in[2];
  const float* W_hh = (const float*)d_in[3];
  const float* b_ih = (const float*)d_in[4];
  const float* b_hh = (const float*)d_in[5];
  const float* pred_W = (const float*)d_in[6];
  const float* pred_b = (const float*)d_in[7];

  float* T1 = (float*)d_ws;       // 30000*128 f32 = 15.36 MB
  float* sbuf = T1 + VROWS * Hd;  // 2*16384 f32
  float* out = (float*)d_out;

  k_t1<<<235, 256, 0, stream>>>(embed, W_ih, b_ih, T1);
  k_rnn<<<16384 / NSEQ, 512, 0, stream>>>(x, T1, W_ih, W_hh, b_ih, b_hh,
                                          pred_W, sbuf);
  k_final<<<4, 1024, 0, stream>>>(sbuf, pred_b, out);
}